// Round 2
// baseline (593.705 us; speedup 1.0000x reference)
//
#include <hip/hip_runtime.h>

// Masked 3x3 conv as implicit GEMM, bf16 MFMA.
//   C[f][n] = sum_{tap,c} Wt[f][tap*512+c] * Xt[(h+dh)*194+(w+dw)][c]
//   out = C*mask + bias
// Round 2: A-operand direct global->VGPR (prefetched 1 iter ahead, no LDS),
// B-operand LDS-staged via global_load_lds with XOR bank swizzle.
// GEMM: M=512 (f), N=36864 (pixels), K=4608. 128x128 tile, BK=32,
// 256 threads = 4 waves, each wave 64x64 via 4x4 mfma_f32_16x16x32_bf16.

typedef unsigned short ushort_t;
typedef __attribute__((ext_vector_type(8))) __bf16 bf16x8;
typedef __attribute__((ext_vector_type(4))) float f32x4;
typedef __attribute__((ext_vector_type(8))) unsigned short ushort8;

#define IMG_W 192
#define IMG_H 192
#define HW    36864       // 192*192
#define PAD_W 194
#define C_IN  512
#define F_OUT 512
#define KTOT  4608        // 9*512

__device__ __forceinline__ unsigned short f2bf(float f) {
  unsigned int u = __builtin_bit_cast(unsigned int, f);
  u += 0x7fffu + ((u >> 16) & 1u);
  return (unsigned short)(u >> 16);
}

__device__ __forceinline__ void async16(const void* g, void* l) {
  // 16B/lane global->LDS DMA; LDS dest is wave-uniform base + lane*16
  __builtin_amdgcn_global_load_lds(
      (const __attribute__((address_space(1))) unsigned int*)g,
      (__attribute__((address_space(3))) unsigned int*)l, 16, 0, 0);
}

// ---------------- prep: zero the 1-px halo of Xt (replaces 38.5MB memset) ----
// 772 halo pixels, one block each: rows 0/193 (194 px each) + cols 0/193 (192 rows)
__global__ void halo_zero(ushort_t* __restrict__ Xt) {
  int p = blockIdx.x;
  int r, c;
  if (p < 388) { r = (p >= 194) ? 193 : 0; c = (p >= 194) ? p - 194 : p; }
  else         { int q = p - 388; r = 1 + (q >> 1); c = (q & 1) ? 193 : 0; }
  unsigned int* dst = (unsigned int*)(Xt + ((size_t)r * PAD_W + c) * C_IN);
  dst[threadIdx.x] = 0;   // 256 threads x 4B = 512 bf16
}

// ---------------- prep: x NCHW fp32 -> padded NHWC bf16 ----------------
__global__ void prep_x(const float* __restrict__ x, ushort_t* __restrict__ Xt) {
  __shared__ float tile[64][65];
  const int tid = threadIdx.x;
  const int h  = blockIdx.z;
  const int w0 = blockIdx.x * 64;
  const int c0 = blockIdx.y * 64;

  const int wl_r = tid & 63;
  const int cg_r = tid >> 6;
  const float* src = x + (size_t)(c0 + cg_r * 16) * HW + (size_t)h * IMG_W + w0 + wl_r;
#pragma unroll
  for (int cc = 0; cc < 16; ++cc)
    tile[cg_r * 16 + cc][wl_r] = src[(size_t)cc * HW];
  __syncthreads();

  const int wl = tid >> 2;
  const int cg = tid & 3;
  ushort_t* dst = Xt + ((size_t)(h + 1) * PAD_W + (w0 + wl + 1)) * C_IN + c0 + cg * 16;
  ushort8 v0, v1;
#pragma unroll
  for (int cc = 0; cc < 8; ++cc) v0[cc] = f2bf(tile[cg * 16 + cc][wl]);
#pragma unroll
  for (int cc = 0; cc < 8; ++cc) v1[cc] = f2bf(tile[cg * 16 + 8 + cc][wl]);
  *(ushort8*)dst = v0;
  *(ushort8*)(dst + 8) = v1;
}

// ---------------- prep: w [f][c][3][3] fp32 -> Wt [f][tap*512+c] bf16 ------
// thread <-> (f,c): reads 9 contiguous floats, writes are lane-contiguous per tap
__global__ void prep_w(const float* __restrict__ w, ushort_t* __restrict__ Wt) {
  const int idx = blockIdx.x * 256 + threadIdx.x;   // f*512 + c
  const int f = idx >> 9;
  const int c = idx & 511;
  const float* src = w + (size_t)idx * 9;
  float v[9];
#pragma unroll
  for (int t = 0; t < 9; ++t) v[t] = src[t];
  ushort_t* dst = Wt + (size_t)f * KTOT + c;
#pragma unroll
  for (int t = 0; t < 9; ++t) dst[t * C_IN] = f2bf(v[t]);
}

// ---------------- implicit GEMM + mask/bias epilogue ----------------
__global__ __launch_bounds__(256) void conv_gemm(
    const ushort_t* __restrict__ Wt, const ushort_t* __restrict__ Xt,
    const float* __restrict__ bias, const int* __restrict__ mask,
    float* __restrict__ out) {
  __shared__ __align__(16) ushort_t Bs[128 * 32];  // [n 0..127][k 0..31], XOR-swizzled

  const int tid  = threadIdx.x;
  const int lane = tid & 63;
  const int wave = tid >> 6;
  const int wm   = wave >> 1;
  const int wn   = wave & 1;
  const int m0   = blockIdx.y * 128;
  const int n0   = blockIdx.x * 128;

  // ---- B staging: thread -> (pixel row nl, phys 16B slot tid&3) ----
  // phys slot p holds logical k-chunk q = p ^ ((row>>1)&3)  (bank swizzle)
  const int nl = tid >> 2;
  const int kq_log = (tid & 3) ^ ((tid >> 3) & 3);
  const int n_a = n0 + nl;
  const int n_b = n_a + 64;
  const int ha = n_a / IMG_W, wa = n_a - ha * IMG_W;
  const int hb = n_b / IMG_W, wb = n_b - hb * IMG_W;
  const ushort_t* bSrcA = Xt + ((size_t)(ha + 1) * PAD_W + (wa + 1)) * C_IN + kq_log * 8;
  const ushort_t* bSrcB = Xt + ((size_t)(hb + 1) * PAD_W + (wb + 1)) * C_IN + kq_log * 8;
  ushort_t* bDstA = &Bs[wave * 512];          // HW adds lane*16B
  ushort_t* bDstB = &Bs[2048 + wave * 512];

  // ---- A direct: each fragment is 16B contiguous in Wt ----
  const int col  = lane & 15;
  const int quad = lane >> 4;
  const ushort_t* aBase = Wt + (size_t)(m0 + wm * 64 + col) * KTOT + quad * 8;

  // ---- B fragment read offsets (apply same XOR swizzle) ----
  const int physq = quad ^ ((col >> 1) & 3);
  const int bOff  = (wn * 64 + col) * 32 + physq * 8;   // + j*512 per n-subtile

  f32x4 acc[4][4] = {};
  bf16x8 afc[4], afn[4];
#pragma unroll
  for (int i = 0; i < 4; ++i)
    afc[i] = *(const bf16x8*)(aBase + (size_t)i * 16 * KTOT);   // koff = 0

  int koff = 0;
#pragma unroll 1
  for (int tap = 0; tap < 9; ++tap) {
    const int toff = ((tap / 3) * PAD_W + (tap % 3) - (PAD_W + 1)) * C_IN;
    const ushort_t* bA = bSrcA + toff;
    const ushort_t* bB = bSrcB + toff;
#pragma unroll 1
    for (int kc = 0; kc < 512; kc += 32) {
      async16(bA + kc, bDstA);
      async16(bB + kc, bDstB);
      // prefetch next iteration's A fragments (latency hides under B drain)
      int koff_n = koff + 32;
      if (koff_n > 4576) koff_n = 4576;   // clamp: stay in-bounds on last iter
#pragma unroll
      for (int i = 0; i < 4; ++i)
        afn[i] = *(const bf16x8*)(aBase + (size_t)i * 16 * KTOT + koff_n);
      __syncthreads();   // drains B async + A prefetch

      bf16x8 bfr[4];
#pragma unroll
      for (int j = 0; j < 4; ++j) bfr[j] = *(const bf16x8*)&Bs[bOff + j * 512];
#pragma unroll
      for (int i = 0; i < 4; ++i)
#pragma unroll
        for (int j = 0; j < 4; ++j)
          acc[i][j] = __builtin_amdgcn_mfma_f32_16x16x32_bf16(afc[i], bfr[j], acc[i][j], 0, 0, 0);
      __syncthreads();
#pragma unroll
      for (int i = 0; i < 4; ++i) afc[i] = afn[i];
      koff += 32;
    }
  }

  // epilogue: out = acc*mask + bias   (C/D: col=lane&15, row=quad*4+r)
#pragma unroll
  for (int j = 0; j < 4; ++j) {
    const int n = n0 + wn * 64 + j * 16 + col;
    const float mv = (float)mask[n];
#pragma unroll
    for (int i = 0; i < 4; ++i) {
      const int mrow = m0 + wm * 64 + i * 16 + quad * 4;
      float* o = out + (size_t)mrow * HW + n;
#pragma unroll
      for (int r = 0; r < 4; ++r)
        o[(size_t)r * HW] = acc[i][j][r] * mv + bias[mrow + r];
    }
  }
}

extern "C" void kernel_launch(void* const* d_in, const int* in_sizes, int n_in,
                              void* d_out, int out_size, void* d_ws, size_t ws_size,
                              hipStream_t stream) {
  const float* x    = (const float*)d_in[0];  // [512][192][192]
  const float* w    = (const float*)d_in[1];  // [512][512][3][3]
  const float* bias = (const float*)d_in[2];  // [512]
  const int*   mask = (const int*)d_in[3];    // [192][192]
  float* out = (float*)d_out;                 // [512][192][192]

  ushort_t* Xt = (ushort_t*)d_ws;                                   // 194*194*512 bf16
  ushort_t* Wt = (ushort_t*)d_ws + (size_t)PAD_W * PAD_W * C_IN;    // 512*4608 bf16

  halo_zero<<<dim3(772), 256, 0, stream>>>(Xt);
  prep_x<<<dim3(3, 8, 192), 256, 0, stream>>>(x, Xt);
  prep_w<<<dim3((F_OUT * C_IN) / 256), 256, 0, stream>>>(w, Wt);
  conv_gemm<<<dim3(HW / 128, F_OUT / 128), 256, 0, stream>>>(Wt, Xt, bias, mask, out);
}

// Round 3
// 306.978 us; speedup vs baseline: 1.9340x; 1.9340x over previous
//
#include <hip/hip_runtime.h>

// Masked 3x3 conv as implicit GEMM over GATHERED pixels (mask==1 only).
//   C[f][p] = sum_{tap,c} Wt[f][tap*512+c] * Xt[(h_p+dh)*194+(w_p+dw)][c]
//   out[f][pix(p)] = C[f][p] + bias[f];  out[f][n] = bias[f] where mask[n]==0
// Round 3: R1 two-operand global_load_lds structure + XOR bank swizzle on
// both A and B fragment reads (validated in R2: conflicts -> 0), plus
// mask-compaction so the GEMM does ~half the work (N ~= 18.4k of 36864).

typedef unsigned short ushort_t;
typedef __attribute__((ext_vector_type(8))) __bf16 bf16x8;
typedef __attribute__((ext_vector_type(4))) float f32x4;
typedef __attribute__((ext_vector_type(8))) unsigned short ushort8;

#define IMG_W 192
#define IMG_H 192
#define HW    36864       // 192*192
#define PAD_W 194
#define C_IN  512
#define F_OUT 512
#define KTOT  4608        // 9*512

__device__ __forceinline__ unsigned short f2bf(float f) {
  unsigned int u = __builtin_bit_cast(unsigned int, f);
  u += 0x7fffu + ((u >> 16) & 1u);
  return (unsigned short)(u >> 16);
}

__device__ __forceinline__ void async16(const void* g, void* l) {
  // 16B/lane global->LDS DMA; LDS dest is wave-uniform base + lane*16
  __builtin_amdgcn_global_load_lds(
      (const __attribute__((address_space(1))) unsigned int*)g,
      (__attribute__((address_space(3))) unsigned int*)l, 16, 0, 0);
}

// ---------------- prep: zero the 1-px halo of Xt ----------------
__global__ void halo_zero(ushort_t* __restrict__ Xt) {
  int p = blockIdx.x;
  int r, c;
  if (p < 388) { r = (p >= 194) ? 193 : 0; c = (p >= 194) ? p - 194 : p; }
  else         { int q = p - 388; r = 1 + (q >> 1); c = (q & 1) ? 193 : 0; }
  unsigned int* dst = (unsigned int*)(Xt + ((size_t)r * PAD_W + c) * C_IN);
  dst[threadIdx.x] = 0;   // 256 threads x 4B = 512 bf16
}

// ---------------- prep: x NCHW fp32 -> padded NHWC bf16 ----------------
__global__ void prep_x(const float* __restrict__ x, ushort_t* __restrict__ Xt) {
  __shared__ float tile[64][65];
  const int tid = threadIdx.x;
  const int h  = blockIdx.z;
  const int w0 = blockIdx.x * 64;
  const int c0 = blockIdx.y * 64;

  const int wl_r = tid & 63;
  const int cg_r = tid >> 6;
  const float* src = x + (size_t)(c0 + cg_r * 16) * HW + (size_t)h * IMG_W + w0 + wl_r;
#pragma unroll
  for (int cc = 0; cc < 16; ++cc)
    tile[cg_r * 16 + cc][wl_r] = src[(size_t)cc * HW];
  __syncthreads();

  const int wl = tid >> 2;
  const int cg = tid & 3;
  ushort_t* dst = Xt + ((size_t)(h + 1) * PAD_W + (w0 + wl + 1)) * C_IN + c0 + cg * 16;
  ushort8 v0, v1;
#pragma unroll
  for (int cc = 0; cc < 8; ++cc) v0[cc] = f2bf(tile[cg * 16 + cc][wl]);
#pragma unroll
  for (int cc = 0; cc < 8; ++cc) v1[cc] = f2bf(tile[cg * 16 + 8 + cc][wl]);
  *(ushort8*)dst = v0;
  *(ushort8*)(dst + 8) = v1;
}

// ---------------- prep: w [f][c][3][3] fp32 -> Wt [f][tap*512+c] bf16 ------
__global__ void prep_w(const float* __restrict__ w, ushort_t* __restrict__ Wt) {
  const int idx = blockIdx.x * 256 + threadIdx.x;   // f*512 + c
  const int f = idx >> 9;
  const int c = idx & 511;
  const float* src = w + (size_t)idx * 9;
  float v[9];
#pragma unroll
  for (int t = 0; t < 9; ++t) v[t] = src[t];
  ushort_t* dst = Wt + (size_t)f * KTOT + c;
#pragma unroll
  for (int t = 0; t < 9; ++t) dst[t * C_IN] = f2bf(v[t]);
}

// ---------------- compact: pixel ids where mask==1 (wave-aggregated) -------
__global__ void compact(const int* __restrict__ mask, int* __restrict__ list,
                        int* __restrict__ counter) {
  const int i = blockIdx.x * 256 + threadIdx.x;
  const int lane = threadIdx.x & 63;
  const int m = mask[i];
  unsigned long long b = __ballot(m != 0);
  int base = 0;
  if (lane == 0 && b) base = atomicAdd(counter, __popcll(b));
  base = __shfl(base, 0);
  if (m) list[base + __popcll(b & ((1ull << lane) - 1ull))] = i;
}

// ---------------- bias fill where mask==0 ----------------
__global__ void bias_fill(const int* __restrict__ mask, const float* __restrict__ bias,
                          float* __restrict__ out) {
  const int n = (blockIdx.x * 256 + threadIdx.x) * 4;   // grid.x = 36
  const int f = blockIdx.y;
  const float bv = bias[f];
  const int4 m = *(const int4*)(mask + n);
  float* o = out + (size_t)f * HW + n;
  if (!m.x) o[0] = bv;
  if (!m.y) o[1] = bv;
  if (!m.z) o[2] = bv;
  if (!m.w) o[3] = bv;
}

// ---------------- implicit GEMM over gathered pixels ----------------
__global__ __launch_bounds__(256) void conv_gemm(
    const ushort_t* __restrict__ Wt, const ushort_t* __restrict__ Xt,
    const float* __restrict__ bias, const int* __restrict__ list,
    const int* __restrict__ counter, float* __restrict__ out) {
  __shared__ __align__(16) ushort_t As[128 * 32];  // [m][k], XOR-swizzled
  __shared__ __align__(16) ushort_t Bs[128 * 32];  // [p][k], XOR-swizzled

  const int count = counter[0];
  const int n0 = blockIdx.x * 128;
  if (n0 >= count) return;

  const int tid  = threadIdx.x;
  const int lane = tid & 63;
  const int wave = tid >> 6;
  const int wm   = wave >> 1;
  const int wn   = wave & 1;
  const int m0   = blockIdx.y * 128;

  // ---- staging roles: row = tid>>2 (+64 for 2nd issue), phys slot tid&3 ----
  // phys slot p at row r holds logical chunk p ^ ((r>>1)&3); permute SOURCE.
  const int nl = tid >> 2;
  const int kq_log = (tid & 3) ^ ((tid >> 3) & 3);
  const int posA = n0 + nl;
  const int posB = posA + 64;
  const int pixA = (posA < count) ? list[posA] : 0;
  const int pixB = (posB < count) ? list[posB] : 0;
  const int ha = pixA / IMG_W, wa = pixA - ha * IMG_W;
  const int hb = pixB / IMG_W, wb = pixB - hb * IMG_W;
  const ushort_t* bSrcA = Xt + ((size_t)(ha + 1) * PAD_W + (wa + 1)) * C_IN + kq_log * 8;
  const ushort_t* bSrcB = Xt + ((size_t)(hb + 1) * PAD_W + (wb + 1)) * C_IN + kq_log * 8;
  const ushort_t* aSrcA = Wt + (size_t)(m0 + nl) * KTOT + kq_log * 8;
  const ushort_t* aSrcB = aSrcA + (size_t)64 * KTOT;

  // wave-uniform LDS dest bases (HW adds lane*16B)
  ushort_t* aDstA = &As[wave * 512];
  ushort_t* aDstB = &As[2048 + wave * 512];
  ushort_t* bDstA = &Bs[wave * 512];
  ushort_t* bDstB = &Bs[2048 + wave * 512];

  f32x4 acc[4][4] = {};

  const int col   = lane & 15;
  const int quad  = lane >> 4;
  const int physq = quad ^ ((col >> 1) & 3);
  const int aOff  = (wm * 64 + col) * 32 + physq * 8;  // + i*512 per m-subtile
  const int bOff  = (wn * 64 + col) * 32 + physq * 8;  // + j*512 per n-subtile

#pragma unroll 1
  for (int tap = 0; tap < 9; ++tap) {
    const int toff = ((tap / 3) * PAD_W + (tap % 3) - (PAD_W + 1)) * C_IN;
    const ushort_t* bA = bSrcA + toff;
    const ushort_t* bB = bSrcB + toff;
    const ushort_t* aA = aSrcA + tap * 512;
    const ushort_t* aB = aSrcB + tap * 512;
#pragma unroll 1
    for (int kc = 0; kc < 512; kc += 32) {
      async16(aA + kc, aDstA);
      async16(aB + kc, aDstB);
      async16(bA + kc, bDstA);
      async16(bB + kc, bDstB);
      __syncthreads();

      bf16x8 af[4], bfr[4];
#pragma unroll
      for (int i = 0; i < 4; ++i) af[i]  = *(const bf16x8*)&As[aOff + i * 512];
#pragma unroll
      for (int j = 0; j < 4; ++j) bfr[j] = *(const bf16x8*)&Bs[bOff + j * 512];
#pragma unroll
      for (int i = 0; i < 4; ++i)
#pragma unroll
        for (int j = 0; j < 4; ++j)
          acc[i][j] = __builtin_amdgcn_mfma_f32_16x16x32_bf16(af[i], bfr[j], acc[i][j], 0, 0, 0);
      __syncthreads();
    }
  }

  // epilogue: out[mrow][pix] = acc + bias   (C/D: col=lane&15, row=quad*4+r)
#pragma unroll
  for (int j = 0; j < 4; ++j) {
    const int pos = n0 + wn * 64 + j * 16 + col;
    if (pos < count) {
      const int n_pix = list[pos];
#pragma unroll
      for (int i = 0; i < 4; ++i) {
        const int mrow = m0 + wm * 64 + i * 16 + quad * 4;
        float* o = out + (size_t)mrow * HW + n_pix;
#pragma unroll
        for (int r = 0; r < 4; ++r)
          o[(size_t)r * HW] = acc[i][j][r] + bias[mrow + r];
      }
    }
  }
}

extern "C" void kernel_launch(void* const* d_in, const int* in_sizes, int n_in,
                              void* d_out, int out_size, void* d_ws, size_t ws_size,
                              hipStream_t stream) {
  const float* x    = (const float*)d_in[0];  // [512][192][192]
  const float* w    = (const float*)d_in[1];  // [512][512][3][3]
  const float* bias = (const float*)d_in[2];  // [512]
  const int*   mask = (const int*)d_in[3];    // [192][192]
  float* out = (float*)d_out;                 // [512][192][192]

  // ws layout: list (36864 int) | counter (1 int, padded) | Xt | Wt
  int* list    = (int*)d_ws;
  int* counter = list + HW;
  ushort_t* Xt = (ushort_t*)((char*)d_ws + 147712);           // 16B-aligned
  ushort_t* Wt = Xt + (size_t)PAD_W * PAD_W * C_IN;
  // total ws need ~43.4 MB

  hipMemsetAsync(counter, 0, sizeof(int), stream);
  compact<<<dim3(HW / 256), 256, 0, stream>>>(mask, list, counter);
  halo_zero<<<dim3(772), 256, 0, stream>>>(Xt);
  prep_x<<<dim3(3, 8, 192), 256, 0, stream>>>(x, Xt);
  prep_w<<<dim3((F_OUT * C_IN) / 256), 256, 0, stream>>>(w, Wt);
  bias_fill<<<dim3(HW / 1024, F_OUT), 256, 0, stream>>>(mask, bias, out);
  conv_gemm<<<dim3((HW + 127) / 128, F_OUT / 128), 256, 0, stream>>>(
      Wt, Xt, bias, list, counter, out);
}

// Round 4
// 264.513 us; speedup vs baseline: 2.2445x; 1.1605x over previous
//
#include <hip/hip_runtime.h>

// Masked 3x3 conv as implicit GEMM over GATHERED pixels (mask==1 only).
//   C[f][p] = sum_{tap,c} Wt[f][tap*512+c] * Xt[(h_p+dh)*194+(w_p+dw)][c]
//   out = bias everywhere (prep_all), then out[f][pix(p)] = C[f][p]+bias[f].
// Round 4: 3 dispatches total (prep_all / compact / conv). Conv uses BK=64
// (32 MFMAs per barrier, 72 iters) with issue-after-read DMA ordering so the
// global_load_lds drain overlaps the previous chunk's MFMA burst.

typedef unsigned short ushort_t;
typedef __attribute__((ext_vector_type(8))) __bf16 bf16x8;
typedef __attribute__((ext_vector_type(4))) float f32x4;
typedef __attribute__((ext_vector_type(8))) unsigned short ushort8;

#define IMG_W 192
#define IMG_H 192
#define HW    36864       // 192*192
#define PAD_W 194
#define C_IN  512
#define F_OUT 512
#define KTOT  4608        // 9*512

__device__ __forceinline__ unsigned short f2bf(float f) {
  unsigned int u = __builtin_bit_cast(unsigned int, f);
  u += 0x7fffu + ((u >> 16) & 1u);
  return (unsigned short)(u >> 16);
}

__device__ __forceinline__ void async16(const void* g, void* l) {
  // 16B/lane global->LDS DMA; LDS dest is wave-uniform base + lane*16
  __builtin_amdgcn_global_load_lds(
      (const __attribute__((address_space(1))) unsigned int*)g,
      (__attribute__((address_space(3))) unsigned int*)l, 16, 0, 0);
}

// ============ prep_all: fused independent prep (1 dispatch) ============
// blocks [0,4608):      prep_x  (x NCHW fp32 -> padded NHWC bf16 interior)
// blocks [4608,5380):   halo_zero (772 border pixels of Xt)
// blocks [5380,6404):   prep_w  (w [f][c][3][3] -> Wt [f][tap*512+c])
// block  6404:          zero compaction counter
// blocks [6405,24837):  bias broadcast: out[f][*] = bias[f] (full lines)
__global__ void prep_all(const float* __restrict__ x, const float* __restrict__ w,
                         const float* __restrict__ bias,
                         ushort_t* __restrict__ Xt, ushort_t* __restrict__ Wt,
                         int* __restrict__ counter, float* __restrict__ out) {
  __shared__ float tile[64][65];
  const int bid = blockIdx.x;
  const int tid = threadIdx.x;

  if (bid < 4608) {
    // ---- prep_x ---- (original R3 body; 64c x 64w LDS transpose)
    const int p  = bid;
    const int w0 = (p % 3) * 64;
    const int c0 = ((p / 3) & 7) * 64;
    const int h  = p / 24;

    const int wl_r = tid & 63;
    const int cg_r = tid >> 6;
    const float* src = x + (size_t)(c0 + cg_r * 16) * HW + (size_t)h * IMG_W + w0 + wl_r;
#pragma unroll
    for (int cc = 0; cc < 16; ++cc)
      tile[cg_r * 16 + cc][wl_r] = src[(size_t)cc * HW];
    __syncthreads();

    const int wl = tid >> 2;
    const int cg = tid & 3;
    ushort_t* dst = Xt + ((size_t)(h + 1) * PAD_W + (w0 + wl + 1)) * C_IN + c0 + cg * 16;
    ushort8 v0, v1;
#pragma unroll
    for (int cc = 0; cc < 8; ++cc) v0[cc] = f2bf(tile[cg * 16 + cc][wl]);
#pragma unroll
    for (int cc = 0; cc < 8; ++cc) v1[cc] = f2bf(tile[cg * 16 + 8 + cc][wl]);
    *(ushort8*)dst = v0;
    *(ushort8*)(dst + 8) = v1;
  } else if (bid < 5380) {
    // ---- halo_zero ----
    const int p = bid - 4608;
    int r, c;
    if (p < 388) { r = (p >= 194) ? 193 : 0; c = (p >= 194) ? p - 194 : p; }
    else         { int q = p - 388; r = 1 + (q >> 1); c = (q & 1) ? 193 : 0; }
    unsigned int* dst = (unsigned int*)(Xt + ((size_t)r * PAD_W + c) * C_IN);
    dst[tid] = 0;
  } else if (bid < 6404) {
    // ---- prep_w ----
    const int idx = (bid - 5380) * 256 + tid;   // f*512 + c
    const int f = idx >> 9;
    const int c = idx & 511;
    const float* src = w + (size_t)idx * 9;
    float v[9];
#pragma unroll
    for (int t = 0; t < 9; ++t) v[t] = src[t];
    ushort_t* dst = Wt + (size_t)f * KTOT + c;
#pragma unroll
    for (int t = 0; t < 9; ++t) dst[t * C_IN] = f2bf(v[t]);
  } else if (bid == 6404) {
    if (tid == 0) *counter = 0;
  } else {
    // ---- bias broadcast (float4 full lines) ----
    const int n4 = (bid - 6405) * 256 + tid;    // 18432*256 = 4.71M float4s
    const int f  = n4 / (HW / 4);
    const int r4 = n4 - f * (HW / 4);
    f32x4 bv = {bias[f], bias[f], bias[f], bias[f]};
    *(f32x4*)(out + (size_t)f * HW + (size_t)r4 * 4) = bv;
  }
}

// ---------------- compact: pixel ids where mask==1 (wave-aggregated) -------
__global__ void compact(const int* __restrict__ mask, int* __restrict__ list,
                        int* __restrict__ counter) {
  const int i = blockIdx.x * 256 + threadIdx.x;
  const int lane = threadIdx.x & 63;
  const int m = mask[i];
  unsigned long long b = __ballot(m != 0);
  int base = 0;
  if (lane == 0 && b) base = atomicAdd(counter, __popcll(b));
  base = __shfl(base, 0);
  if (m) list[base + __popcll(b & ((1ull << lane) - 1ull))] = i;
}

// ---------------- implicit GEMM over gathered pixels, BK=64 ----------------
__global__ __launch_bounds__(256, 3) void conv_gemm(
    const ushort_t* __restrict__ Wt, const ushort_t* __restrict__ Xt,
    const float* __restrict__ bias, const int* __restrict__ list,
    const int* __restrict__ counter, float* __restrict__ out) {
  __shared__ __align__(16) ushort_t As[128 * 64];  // [m 0..127][k 0..63], swizzled
  __shared__ __align__(16) ushort_t Bs[128 * 64];  // [p 0..127][k 0..63], swizzled

  const int count = counter[0];
  const int n0 = blockIdx.x * 128;
  if (n0 >= count) return;

  const int tid  = threadIdx.x;
  const int lane = tid & 63;
  const int wave = tid >> 6;
  const int wm   = wave >> 1;
  const int wn   = wave & 1;
  const int m0   = blockIdx.y * 128;

  // ---- staging role: wave w stages rows [w*32, w*32+32) of A and B, via
  // 4 issues of 1KB (8 rows each). lane -> (row_rel = lane>>3, phys = lane&7).
  // Swizzle: phys slot p at row r holds logical chunk p ^ (r&7); here
  // r&7 == lane>>3, so each lane's logical chunk q is loop-invariant.
  const int rrel = lane >> 3;
  const int q    = (lane & 7) ^ rrel;

  const ushort_t* aSrc = Wt + (size_t)(m0 + wave * 32 + rrel) * KTOT + q * 8;

  unsigned int bOffs[4];
#pragma unroll
  for (int ii = 0; ii < 4; ++ii) {
    const int pos = n0 + wave * 32 + ii * 8 + rrel;
    const int pix = (pos < count) ? list[pos] : 0;
    const int hh = pix / IMG_W, ww = pix - hh * IMG_W;
    bOffs[ii] = ((hh + 1) * PAD_W + (ww + 1)) * C_IN + q * 8;
  }

  ushort_t* aDst = &As[wave * 32 * 64];  // + ii*512 per issue (8 rows x 64)
  ushort_t* bDst = &Bs[wave * 32 * 64];

  const int col  = lane & 15;
  const int quad = lane >> 4;

  f32x4 acc[4][4] = {};

  // initial staging (kk=0: tap 0, kc 0)
  {
    const int toff0 = -(PAD_W + 1) * C_IN;
#pragma unroll
    for (int ii = 0; ii < 4; ++ii) {
      async16(aSrc + (size_t)ii * 8 * KTOT, aDst + ii * 512);
      async16(Xt + (int)bOffs[ii] + toff0, bDst + ii * 512);
    }
  }

#pragma unroll 1
  for (int kk = 0; kk < 72; ++kk) {
    __syncthreads();   // staging for kk ready (drains vmcnt; DMA was in
                       // flight during the previous chunk's MFMA burst)
    bf16x8 af[2][4], bfr[2][4];
#pragma unroll
    for (int s = 0; s < 2; ++s) {
#pragma unroll
      for (int i = 0; i < 4; ++i) {
        const int row = wm * 64 + i * 16 + col;
        af[s][i] = *(const bf16x8*)&As[row * 64 + ((s * 4 + quad) ^ (row & 7)) * 8];
      }
#pragma unroll
      for (int j = 0; j < 4; ++j) {
        const int row = wn * 64 + j * 16 + col;
        bfr[s][j] = *(const bf16x8*)&Bs[row * 64 + ((s * 4 + quad) ^ (row & 7)) * 8];
      }
    }
    if (kk < 71) {
      __syncthreads();   // all waves done reading LDS; safe to overwrite
      const int kn   = kk + 1;
      const int tapn = kn >> 3;
      const int kcn  = (kn & 7) * 64;
      const int toffn = ((tapn / 3) * PAD_W + (tapn % 3) - (PAD_W + 1)) * C_IN;
      const int aoffn = tapn * 512 + kcn;
#pragma unroll
      for (int ii = 0; ii < 4; ++ii) {
        async16(aSrc + (size_t)ii * 8 * KTOT + aoffn, aDst + ii * 512);
        async16(Xt + (int)bOffs[ii] + toffn + kcn, bDst + ii * 512);
      }
    }
#pragma unroll
    for (int s = 0; s < 2; ++s)
#pragma unroll
      for (int i = 0; i < 4; ++i)
#pragma unroll
        for (int j = 0; j < 4; ++j)
          acc[i][j] = __builtin_amdgcn_mfma_f32_16x16x32_bf16(af[s][i], bfr[s][j],
                                                              acc[i][j], 0, 0, 0);
  }

  // epilogue: out[mrow][pix] = acc + bias   (C/D: col=lane&15, row=quad*4+r)
#pragma unroll
  for (int j = 0; j < 4; ++j) {
    const int pos = n0 + wn * 64 + j * 16 + col;
    if (pos < count) {
      const int n_pix = list[pos];
#pragma unroll
      for (int i = 0; i < 4; ++i) {
        const int mrow = m0 + wm * 64 + i * 16 + quad * 4;
        float* o = out + (size_t)mrow * HW + n_pix;
#pragma unroll
        for (int r = 0; r < 4; ++r)
          o[(size_t)r * HW] = acc[i][j][r] + bias[mrow + r];
      }
    }
  }
}

extern "C" void kernel_launch(void* const* d_in, const int* in_sizes, int n_in,
                              void* d_out, int out_size, void* d_ws, size_t ws_size,
                              hipStream_t stream) {
  const float* x    = (const float*)d_in[0];  // [512][192][192]
  const float* w    = (const float*)d_in[1];  // [512][512][3][3]
  const float* bias = (const float*)d_in[2];  // [512]
  const int*   mask = (const int*)d_in[3];    // [192][192]
  float* out = (float*)d_out;                 // [512][192][192]

  // ws layout: list (36864 int) | counter | pad | Xt (38.5MB) | Wt (4.7MB)
  int* list    = (int*)d_ws;
  int* counter = list + HW;
  ushort_t* Xt = (ushort_t*)((char*)d_ws + 147712);   // 16B-aligned
  ushort_t* Wt = Xt + (size_t)PAD_W * PAD_W * C_IN;

  prep_all<<<dim3(24837), 256, 0, stream>>>(x, w, bias, Xt, Wt, counter, out);
  compact<<<dim3(HW / 256), 256, 0, stream>>>(mask, list, counter);
  conv_gemm<<<dim3((HW + 127) / 128, F_OUT / 128), 256, 0, stream>>>(
      Wt, Xt, bias, list, counter, out);
}